// Round 16
// baseline (24.727 us; speedup 1.0000x reference)
//
#include <hip/hip_runtime.h>
#include <stdint.h>

#define BB 512
#define TT 500
#define KK 64
#define DD 64

typedef unsigned long long ull;

// One 512-thread block per b. Zero global scratch.
// Waves 1..7 (448 thr) stream the b's chain slice flat-contiguously:
//   bf16: 4000 uint4, f = (tid-64) + 448*i, i<9  -> 8 KB contiguous/round
//   f32 : 8000 uint4, i<18
// Owner lane of the row's unique nonzero uint4 decodes k locally and
// LDS-atomicOr's bit (row&63) into tmask[row>>6][k]. Wave 0 concurrently
// computes per-k params (regs) + stages corr. One barrier; wave 0 (lane=k)
// ctz-walks its ~8 events and writes float2 log-probs.
__launch_bounds__(512, 4)
__global__ void bkt_fused(const uint32_t* __restrict__ chainw,
                          const int* __restrict__ corr,
                          const float* __restrict__ embd,
                          const float* __restrict__ Wf,
                          const float* __restrict__ bias,
                          float2* __restrict__ out) {
    __shared__ ull tmask[8][KK];                 // 4 KB
    __shared__ uint32_t corr_s[TT];              // 2 KB

    const int b = blockIdx.x;
    const int tid = threadIdx.x;
    const int wv = tid >> 6, lane = tid & 63;

    // ---- dtype sniff: f32 one-hot row 0 -> 1 nonzero word in first 64; bf16 -> 2 ----
    uint32_t sv = chainw[lane];
    ull sm = __ballot(sv != 0u);
    const bool isb = (__popcll(sm) >= 2);

    // ---- burst-issue streaming loads (before LDS zero; independent of LDS) ----
    const int st = tid - 64;                     // streaming thread id 0..447
    uint4 r[18];
    int nld = 0;
    if (wv != 0) {
        const uint4* cb4;
        if (isb) {                               // bf16: 4000 uint4 per b
            cb4 = (const uint4*)chainw + ((size_t)b << 12) - b * 96; // b*4000... avoid mul64: computed below
            cb4 = (const uint4*)chainw + (size_t)b * 4000;
            nld = 9;
#pragma unroll
            for (int i = 0; i < 9; ++i) {
                int f = st + 448 * i;
                if (f < 4000) r[i] = cb4[f];
            }
        } else {                                 // f32: 8000 uint4 per b
            cb4 = (const uint4*)chainw + (size_t)b * 8000;
            nld = 18;
#pragma unroll
            for (int i = 0; i < 18; ++i) {
                int f = st + 448 * i;
                if (f < 8000) r[i] = cb4[f];
            }
        }
    }

    // ---- zero bitmap (512 words; one per thread) ----
    ((ull*)tmask)[tid] = 0;

    float g0 = 0.f, g1 = 0.f, t10 = 0.f, t11 = 0.f, p1 = 0.f;
    if (wv == 0) {
        // ---- per-k params in registers (lane = k) ----
        float l0 = bias[0], l1 = bias[1], l2 = bias[2], l3 = bias[3], l4 = bias[4];
        const float4* er = (const float4*)(embd + lane * DD);
#pragma unroll 4
        for (int d4 = 0; d4 < DD / 4; ++d4) {
            float4 e = er[d4];
            float4 a;
            a = ((const float4*)(Wf + 0 * DD))[d4]; l0 = fmaf(e.x,a.x,fmaf(e.y,a.y,fmaf(e.z,a.z,fmaf(e.w,a.w,l0))));
            a = ((const float4*)(Wf + 1 * DD))[d4]; l1 = fmaf(e.x,a.x,fmaf(e.y,a.y,fmaf(e.z,a.z,fmaf(e.w,a.w,l1))));
            a = ((const float4*)(Wf + 2 * DD))[d4]; l2 = fmaf(e.x,a.x,fmaf(e.y,a.y,fmaf(e.z,a.z,fmaf(e.w,a.w,l2))));
            a = ((const float4*)(Wf + 3 * DD))[d4]; l3 = fmaf(e.x,a.x,fmaf(e.y,a.y,fmaf(e.z,a.z,fmaf(e.w,a.w,l3))));
            a = ((const float4*)(Wf + 4 * DD))[d4]; l4 = fmaf(e.x,a.x,fmaf(e.y,a.y,fmaf(e.z,a.z,fmaf(e.w,a.w,l4))));
        }
        auto sig = [](float x) { return 1.0f / (1.0f + __expf(-x)); };
        t10 = sig( 2.f * l0);    // p(s'=1 | s=0)
        t11 = sig(-2.f * l1);    // p(s'=1 | s=1)
        g0  = sig( 2.f * l2);    // p(y=1 | s=0)
        g1  = sig(-2.f * l3);    // p(y=1 | s=1)
        p1  = sig( 2.f * l4);    // initial p(s=1)

        // ---- corr -> LDS ----
        const uint32_t* cp = (const uint32_t*)corr + (size_t)b * TT;
#pragma unroll
        for (int i = 0; i < 8; ++i) {
            int idx = i * 64 + lane;
            if (idx < TT) corr_s[idx] = cp[idx];
        }
    }
    __syncthreads();                             // tmask zeroed, visible

    // ---- decode + deposit ----
    if (wv != 0) {
        if (isb) {
#pragma unroll
            for (int i = 0; i < 9; ++i) {
                int f = st + 448 * i;
                if (f < 4000) {
                    uint4 v = r[i];
                    if ((v.x | v.y | v.z | v.w) != 0u) {
                        int j;
                        if (v.x)      j = (v.x & 0xFFFFu) ? 0 : 1;
                        else if (v.y) j = (v.y & 0xFFFFu) ? 2 : 3;
                        else if (v.z) j = (v.z & 0xFFFFu) ? 4 : 5;
                        else          j = (v.w & 0xFFFFu) ? 6 : 7;
                        int row = f >> 3;
                        int k = (f & 7) * 8 + j;
                        atomicOr(&tmask[row >> 6][k], 1ull << (row & 63));
                    }
                }
            }
        } else {
#pragma unroll
            for (int i = 0; i < 18; ++i) {
                int f = st + 448 * i;
                if (f < 8000) {
                    uint4 v = r[i];
                    if ((v.x | v.y | v.z | v.w) != 0u) {
                        int widx;
                        if (v.x)      widx = 0;
                        else if (v.y) widx = 1;
                        else if (v.z) widx = 2;
                        else          widx = 3;
                        int row = f >> 4;
                        int k = (f & 15) * 4 + widx;
                        atomicOr(&tmask[row >> 6][k], 1ull << (row & 63));
                    }
                }
            }
        }
    }
    __syncthreads();

    // ---- phase 2: wave 0, lane = k: ctz-walk + scalar filter ----
    if (wv == 0) {
        const float dg = g1 - g0, dt = t11 - t10, g1c = 1.f - g1;
        float2* ob = out + (size_t)b * TT;
#pragma unroll
        for (int w = 0; w < 8; ++w) {
            ull tb = tmask[w][lane];
            while (tb) {
                int j = __builtin_ctzll(tb);
                tb &= tb - 1;
                int t = w * 64 + j;
                int yy = (int)(corr_s[t] & 1u);
                float pe1 = fmaf(p1, dg, g0);
                float pe0 = 1.f - pe1;
                ob[t] = make_float2(__logf(pe0), __logf(pe1));
                float gy  = yy ? g1  : g1c;
                float pyy = yy ? pe1 : pe0;
                p1 = fmaf(p1 * __fdividef(gy, pyy), dt, t10);
            }
        }
    }
}

extern "C" void kernel_launch(void* const* d_in, const int* in_sizes, int n_in,
                              void* d_out, int out_size, void* d_ws, size_t ws_size,
                              hipStream_t stream) {
    // Identify inputs by flat element count (robust to ordering).
    const void* p_corr = nullptr, *p_chain = nullptr, *p_embd = nullptr,
              * p_Wf = nullptr, *p_bias = nullptr;
    for (int i = 0; i < n_in; ++i) {
        switch (in_sizes[i]) {
            case BB * TT:        p_corr  = d_in[i]; break;   // 256000
            case BB * TT * KK:   p_chain = d_in[i]; break;   // 16384000
            case KK * DD:        p_embd  = d_in[i]; break;   // 4096
            case 5 * DD:         p_Wf    = d_in[i]; break;   // 320
            case 5:              p_bias  = d_in[i]; break;
            default: break;
        }
    }
    if (!p_corr)  p_corr  = d_in[0];
    if (!p_chain) p_chain = d_in[1];
    if (!p_embd)  p_embd  = d_in[2];
    if (!p_Wf)    p_Wf    = d_in[3];
    if (!p_bias)  p_bias  = d_in[4];
    (void)d_ws; (void)ws_size; (void)out_size;

    bkt_fused<<<BB, 512, 0, stream>>>((const uint32_t*)p_chain,
                                      (const int*)p_corr,
                                      (const float*)p_embd,
                                      (const float*)p_Wf,
                                      (const float*)p_bias,
                                      (float2*)d_out);
}

// Round 17
// 22.506 us; speedup vs baseline: 1.0987x; 1.0987x over previous
//
#include <hip/hip_runtime.h>
#include <stdint.h>

#define BB 512
#define TT 500
#define KK 64
#define DD 64

typedef unsigned long long ull;

// One 512-thread block per batch element b. Zero global scratch.
// Wave w (=t-window) lane l owns row t = w*64+l: finds its one-hot k and
// LDS-atomicOr's bit l into (tmask[w][k], ymask[w][k]). Wave 0 also computes
// the 64 per-k sigmoid params (redundant per block, L2-hot). One barrier;
// then wave 0 lane k ctz-walks its ~8 events and writes float2 log-probs.
__launch_bounds__(512, 4)
__global__ void bkt_fused(const uint32_t* __restrict__ chainw,
                          const int* __restrict__ corr,
                          const float* __restrict__ embd,
                          const float* __restrict__ Wf,
                          const float* __restrict__ bias,
                          float2* __restrict__ out) {
    __shared__ ull tmask[8][KK];
    __shared__ ull ymask[8][KK];

    const int b = blockIdx.x;
    const int tid = threadIdx.x;
    const int wv = tid >> 6, lane = tid & 63;

    // ---- dtype sniff: f32 one-hot row 0 -> 1 nonzero word in first 64; bf16 -> 2 ----
    uint32_t sv = chainw[lane];
    ull sm = __ballot(sv != 0u);
    const bool isb = (__popcll(sm) >= 2);

    // ---- zero this wave's LDS slice (wave-synchronous; no barrier needed) ----
    tmask[wv][lane] = 0;
    ymask[wv][lane] = 0;

    const int t = wv * 64 + lane;
    const bool live = (t < TT);

    int y = 0;
    if (live) y = corr[b * TT + t] & 1;

    // ---- find one-hot k in this row (independent vector loads) ----
    int k = -1;
    if (isb) {                                   // bf16 row = 128 B = 8 uint4
        const uint4* rp = (const uint4*)chainw + (((size_t)b * TT + t) << 3);
        if (live) {
            uint4 r[8];
#pragma unroll
            for (int q = 0; q < 8; ++q) r[q] = rp[q];
#pragma unroll
            for (int q = 0; q < 8; ++q) {
                uint4 v = r[q];
                if ((v.x | v.y | v.z | v.w) != 0u) {
                    int widx; uint32_t nw;
                    if (v.x)      { widx = 0; nw = v.x; }
                    else if (v.y) { widx = 1; nw = v.y; }
                    else if (v.z) { widx = 2; nw = v.z; }
                    else          { widx = 3; nw = v.w; }
                    k = q * 8 + widx * 2 + ((nw >> 16) ? 1 : 0);
                }
            }
        }
    } else {                                     // f32 row = 256 B = 16 uint4
        const uint4* rp = (const uint4*)chainw + (((size_t)b * TT + t) << 4);
        if (live) {
            uint4 r[16];
#pragma unroll
            for (int q = 0; q < 16; ++q) r[q] = rp[q];
#pragma unroll
            for (int q = 0; q < 16; ++q) {
                uint4 v = r[q];
                if ((v.x | v.y | v.z | v.w) != 0u) {
                    int widx;
                    if (v.x)      widx = 0;
                    else if (v.y) widx = 1;
                    else if (v.z) widx = 2;
                    else          widx = 3;
                    k = q * 4 + widx;
                }
            }
        }
    }

    // ---- per-k params (wave 0 only; overlaps other waves' loads) ----
    float g0, g1, t10, t11, p1;
    if (wv == 0) {
        float l0 = bias[0], l1 = bias[1], l2 = bias[2], l3 = bias[3], l4 = bias[4];
        const float4* er = (const float4*)(embd + lane * DD);
        const float4* w0 = (const float4*)(Wf + 0 * DD);
        const float4* w1 = (const float4*)(Wf + 1 * DD);
        const float4* w2 = (const float4*)(Wf + 2 * DD);
        const float4* w3 = (const float4*)(Wf + 3 * DD);
        const float4* w4 = (const float4*)(Wf + 4 * DD);
#pragma unroll 4
        for (int d4 = 0; d4 < DD / 4; ++d4) {
            float4 e = er[d4];
            float4 a;
            a = w0[d4]; l0 = fmaf(e.x,a.x,fmaf(e.y,a.y,fmaf(e.z,a.z,fmaf(e.w,a.w,l0))));
            a = w1[d4]; l1 = fmaf(e.x,a.x,fmaf(e.y,a.y,fmaf(e.z,a.z,fmaf(e.w,a.w,l1))));
            a = w2[d4]; l2 = fmaf(e.x,a.x,fmaf(e.y,a.y,fmaf(e.z,a.z,fmaf(e.w,a.w,l2))));
            a = w3[d4]; l3 = fmaf(e.x,a.x,fmaf(e.y,a.y,fmaf(e.z,a.z,fmaf(e.w,a.w,l3))));
            a = w4[d4]; l4 = fmaf(e.x,a.x,fmaf(e.y,a.y,fmaf(e.z,a.z,fmaf(e.w,a.w,l4))));
        }
        auto sig = [](float x) { return 1.0f / (1.0f + __expf(-x)); };
        t10 = sig( 2.f * l0);    // p(s'=1 | s=0)
        t11 = sig(-2.f * l1);    // p(s'=1 | s=1)
        g0  = sig( 2.f * l2);    // p(y=1 | s=0)
        g1  = sig(-2.f * l3);    // p(y=1 | s=1)
        p1  = sig( 2.f * l4);    // initial p(s=1)
    }

    // ---- deposit event bits (wave-local LDS atomics, in-order) ----
    if (k >= 0) {
        atomicOr(&tmask[wv][k], 1ull << lane);
        if (y) atomicOr(&ymask[wv][k], 1ull << lane);
    }
    __syncthreads();

    // ---- phase 2: wave 0, lane = k ----
    if (wv == 0) {
        const float dg = g1 - g0, dt = t11 - t10, g1c = 1.f - g1;
        float2* ob = out + (size_t)b * TT;
#pragma unroll
        for (int w = 0; w < 8; ++w) {
            ull tb = tmask[w][lane];
            const ull yb = ymask[w][lane];
            while (tb) {
                int j = __builtin_ctzll(tb);
                tb &= tb - 1;
                int tt = w * 64 + j;
                int yy = (int)((yb >> j) & 1ull);
                float pe1 = fmaf(p1, dg, g0);
                float pe0 = 1.f - pe1;
                ob[tt] = make_float2(__logf(pe0), __logf(pe1));
                float gy  = yy ? g1  : g1c;
                float pyy = yy ? pe1 : pe0;
                p1 = fmaf(p1 * __fdividef(gy, pyy), dt, t10);
            }
        }
    }
}

extern "C" void kernel_launch(void* const* d_in, const int* in_sizes, int n_in,
                              void* d_out, int out_size, void* d_ws, size_t ws_size,
                              hipStream_t stream) {
    // Identify inputs by flat element count (robust to ordering).
    const void* p_corr = nullptr, *p_chain = nullptr, *p_embd = nullptr,
              * p_Wf = nullptr, *p_bias = nullptr;
    for (int i = 0; i < n_in; ++i) {
        switch (in_sizes[i]) {
            case BB * TT:        p_corr  = d_in[i]; break;   // 256000
            case BB * TT * KK:   p_chain = d_in[i]; break;   // 16384000
            case KK * DD:        p_embd  = d_in[i]; break;   // 4096
            case 5 * DD:         p_Wf    = d_in[i]; break;   // 320
            case 5:              p_bias  = d_in[i]; break;
            default: break;
        }
    }
    if (!p_corr)  p_corr  = d_in[0];
    if (!p_chain) p_chain = d_in[1];
    if (!p_embd)  p_embd  = d_in[2];
    if (!p_Wf)    p_Wf    = d_in[3];
    if (!p_bias)  p_bias  = d_in[4];
    (void)d_ws; (void)ws_size; (void)out_size;

    bkt_fused<<<BB, 512, 0, stream>>>((const uint32_t*)p_chain,
                                      (const int*)p_corr,
                                      (const float*)p_embd,
                                      (const float*)p_Wf,
                                      (const float*)p_bias,
                                      (float2*)d_out);
}